// Round 3
// baseline (104.215 us; speedup 1.0000x reference)
//
#include <hip/hip_runtime.h>
#include <math.h>

#define H    64
#define N    256
#define D    128
#define L    16
#define ROWLEN 448                 // cols per i-segment: 128 obs | 64 g | 256 p
#define F3IN (N * ROWLEN)          // 114688
#define ROW4 112                   // float4 per 448-col segment
#define NROWS 512

__device__ __forceinline__ float sigmoidf_(float x) {
    return 1.0f / (1.0f + expf(-x));
}
__device__ __forceinline__ float dot4(float4 a, float4 b) {
    return a.x * b.x + a.y * b.y + a.z * b.z + a.w * b.w;
}

// ---------------------------------------------------------------------------
// K1: blocks 0..2047 stream the obs-part of W1 (64 MiB): partial_obs[bid] =
//     sum over its (row, 64-segment chunk) of W1[r, i*448+c]*obs[i,c], c<128.
//     Block 0 FIRST runs the encoder: emb gather + GRU(L=16) + f1W transform
//     + factorized flat softmax (Z_ij = u_i+v_j+const; const cancels), writing
//     g, eu*scale, ev to ws. Encoder (latency-bound) overlaps the stream.
// ---------------------------------------------------------------------------
__global__ __launch_bounds__(256, 8) void k_obs_enc(
    const float* __restrict__ W1, const float* __restrict__ obs,
    const int* __restrict__ token_ids, const float* __restrict__ emb_table,
    const float* __restrict__ Wih, const float* __restrict__ Whh,
    const float* __restrict__ bih, const float* __restrict__ bhh,
    const float* __restrict__ f1W,
    float* __restrict__ g_out, float* __restrict__ eus_out,
    float* __restrict__ ev_out, float* __restrict__ partial_obs)
{
    // carved LDS (17.3 KB): keeps 8 blocks/CU co-resident
    __shared__ float smem[4416];
    const int t = threadIdx.x;
    const int bid = blockIdx.x;

    if (bid == 0) {
        float* emb_s  = smem;          // [16][64]
        float* gi_all = smem + 1024;   // [16][192] (reused later as wa/wb/red)
        float* h_s    = smem + 4096;   // [64]
        float* hnew_s = smem + 4160;   // [64]
        float* gh_s   = smem + 4224;   // [192]

        for (int idx = t; idx < L * H; idx += 256) {
            int tt = idx >> 6, d = idx & 63;
            emb_s[idx] = emb_table[token_ids[tt] * H + d];
        }
        if (t < H) h_s[t] = 0.0f;
        __syncthreads();

        // gi_all[t][k] = bih[k] + Wih[k,:] . emb[t]  (parallel over k)
        if (t < 3 * H) {
            float gi[L];
#pragma unroll
            for (int tt = 0; tt < L; ++tt) gi[tt] = 0.0f;
            const float4* wr = (const float4*)(Wih + t * H);
#pragma unroll
            for (int c = 0; c < 16; ++c) {
                float4 w = wr[c];
#pragma unroll
                for (int tt = 0; tt < L; ++tt)
                    gi[tt] += dot4(w, ((const float4*)(emb_s + tt * 64))[c]);
            }
            float b = bih[t];
#pragma unroll
            for (int tt = 0; tt < L; ++tt) gi_all[tt * 192 + t] = gi[tt] + b;
        }
        float bh = (t < 3 * H) ? bhh[t] : 0.0f;
        __syncthreads();

        // serial GRU: Whh rows re-read from cache (48 KB, L1/L2-hot)
        for (int tt = 0; tt < L; ++tt) {
            if (t < 3 * H) {
                const float4* wr = (const float4*)(Whh + t * H);
                float gh = bh;
#pragma unroll
                for (int c = 0; c < 16; ++c)
                    gh += dot4(wr[c], ((const float4*)h_s)[c]);
                gh_s[t] = gh;
            }
            __syncthreads();
            if (t < H) {
                float r = sigmoidf_(gi_all[tt * 192 + t] + gh_s[t]);
                float z = sigmoidf_(gi_all[tt * 192 + 64 + t] + gh_s[64 + t]);
                float n = tanhf(gi_all[tt * 192 + 128 + t] + r * gh_s[128 + t]);
                hnew_s[t] = (1.0f - z) * n + z * h_s[t];
            }
            __syncthreads();
            if (t < H) h_s[t] = hnew_s[t];
            __syncthreads();
        }

        // wa = f1W[:, :128]^T g ; wb = f1W[:, 128:]^T g  (gi_all region reused)
        float* wa_s = smem + 1024;   // [128]
        float* wb_s = smem + 1152;   // [128]
        float* red  = smem + 1280;   // [256]
        {
            float s = 0.0f;
#pragma unroll 8
            for (int kk = 0; kk < H; ++kk) s += f1W[kk * (2 * D) + t] * h_s[kk];
            if (t < D) wa_s[t] = s;
            else       wb_s[t - D] = s;
        }
        __syncthreads();

        // u_i = obs_i . wa ; v_i = obs_i . wb  (thread = row i)
        const float4* rowp = (const float4*)(obs + t * D);
        float u = 0.0f, v = 0.0f;
#pragma unroll
        for (int c = 0; c < 32; ++c) {
            float4 o = rowp[c];
            u += dot4(o, ((const float4*)wa_s)[c]);
            v += dot4(o, ((const float4*)wb_s)[c]);
        }

        red[t] = u; __syncthreads();
        for (int s = 128; s > 0; s >>= 1) { if (t < s) red[t] = fmaxf(red[t], red[t + s]); __syncthreads(); }
        const float mu = red[0]; __syncthreads();
        const float eui = expf(u - mu);
        red[t] = eui; __syncthreads();
        for (int s = 128; s > 0; s >>= 1) { if (t < s) red[t] += red[t + s]; __syncthreads(); }
        const float Su = red[0]; __syncthreads();

        red[t] = v; __syncthreads();
        for (int s = 128; s > 0; s >>= 1) { if (t < s) red[t] = fmaxf(red[t], red[t + s]); __syncthreads(); }
        const float mv = red[0]; __syncthreads();
        const float evi = expf(v - mv);
        red[t] = evi; __syncthreads();
        for (int s = 128; s > 0; s >>= 1) { if (t < s) red[t] += red[t + s]; __syncthreads(); }
        const float Sv = red[0]; __syncthreads();

        const float scale = 1.0f / (Su * Sv);
        eus_out[t] = eui * scale;     // fold softmax scale into eu
        ev_out[t]  = evi;
        if (t < H) g_out[t] = h_s[t];
    }

    // ---- obs-part chunk (all 2048 blocks; block 0 after its encoder) ----
    const int row = bid >> 2, q = bid & 3;
    const float4* wbase = (const float4*)W1 + (size_t)row * (F3IN / 4)
                        + (size_t)(q * 64) * ROW4;
    const float4* obs4 = (const float4*)obs + (q * 64) * 32;

    float sum = 0.0f;
#pragma unroll
    for (int k = 0; k < 8; ++k) {
        int idx = t + k * 256;
        int s = idx >> 5, c4 = idx & 31;          // segment, float4-within
        sum += dot4(wbase[s * ROW4 + c4], obs4[s * 32 + c4]);
    }

    float* red2 = smem + 1280;
    __syncthreads();
    red2[t] = sum; __syncthreads();
    for (int s = 128; s > 0; s >>= 1) {
        if (t < s) red2[t] += red2[t + s];
        __syncthreads();
    }
    if (t == 0) partial_obs[bid] = red2[0];
}

// ---------------------------------------------------------------------------
// K2: g-part + p-part of W1 (160 MiB): per row r, segment i, cols
// [i*448+128, i*448+448) = 64 g-cols (dot g) + 256 p-cols (dot ev, * eu_i*scale).
// x is never materialized. 1280 B contiguous runs, 128 B aligned.
// ---------------------------------------------------------------------------
__global__ __launch_bounds__(256, 8) void k_gp(
    const float* __restrict__ W1, const float* __restrict__ g,
    const float* __restrict__ eus, const float* __restrict__ ev,
    float* __restrict__ partial_gp)
{
    __shared__ float g_s[64];
    __shared__ float ev_s[256];
    __shared__ float eu_s[64];
    __shared__ float red[256];

    const int t = threadIdx.x;
    const int row = blockIdx.x >> 2, q = blockIdx.x & 3;

    if (t < 64) { g_s[t] = g[t]; eu_s[t] = eus[q * 64 + t]; }
    ev_s[t] = ev[t];
    __syncthreads();

    const float4* wbase = (const float4*)W1 + (size_t)row * (F3IN / 4)
                        + (size_t)(q * 64) * ROW4 + 32;

    float sum = 0.0f;
#pragma unroll 4
    for (int k = 0; k < 20; ++k) {
        int idx = t + k * 256;                    // 5120 f4 = 64 seg x 80 f4
        int s = idx / 80, c4 = idx - s * 80;
        float4 w = wbase[s * ROW4 + c4];
        if (c4 < 16) sum += dot4(w, ((const float4*)g_s)[c4]);
        else         sum += dot4(w, ((const float4*)ev_s)[c4 - 16]) * eu_s[s];
    }

    red[t] = sum; __syncthreads();
    for (int s = 128; s > 0; s >>= 1) {
        if (t < s) red[t] += red[t + s];
        __syncthreads();
    }
    if (t == 0) partial_gp[blockIdx.x] = red[0];
}

// ---------------------------------------------------------------------------
// K3: h1 = relu(sum of 8 partials + b1); out = W2 @ h1 + b2. One block.
// ---------------------------------------------------------------------------
__global__ __launch_bounds__(512) void k_finish(
    const float* __restrict__ po, const float* __restrict__ pg,
    const float* __restrict__ b1, const float* __restrict__ W2,
    const float* __restrict__ b2, float* __restrict__ out)
{
    __shared__ float h1s[512];
    const int r = threadIdx.x;
    {
        float4 a = ((const float4*)po)[r];
        float4 b = ((const float4*)pg)[r];
        h1s[r] = fmaxf(a.x + a.y + a.z + a.w + b.x + b.y + b.z + b.w + b1[r], 0.0f);
    }
    __syncthreads();

    const int wave = r >> 6, lane = r & 63;
    for (int row = wave; row < 40; row += 8) {
        float s = 0.0f;
#pragma unroll
        for (int c = 0; c < 8; ++c)
            s += W2[row * 512 + lane + c * 64] * h1s[lane + c * 64];
#pragma unroll
        for (int off = 32; off > 0; off >>= 1) s += __shfl_down(s, off, 64);
        if (lane == 0) out[row] = s + b2[row];
    }
}

// ---------------------------------------------------------------------------
extern "C" void kernel_launch(void* const* d_in, const int* in_sizes, int n_in,
                              void* d_out, int out_size, void* d_ws, size_t ws_size,
                              hipStream_t stream)
{
    const float* obs       = (const float*)d_in[0];
    const int*   token_ids = (const int*)  d_in[1];
    const float* emb_table = (const float*)d_in[2];
    const float* Wih       = (const float*)d_in[3];
    const float* Whh       = (const float*)d_in[4];
    const float* bih       = (const float*)d_in[5];
    const float* bhh       = (const float*)d_in[6];
    const float* f1W       = (const float*)d_in[7];
    // d_in[8] = f1_b : cancels in the flat softmax (Z_ij = u_i + v_j + const)
    const float* W1        = (const float*)d_in[9];
    const float* b1        = (const float*)d_in[10];
    const float* W2        = (const float*)d_in[11];
    const float* b2        = (const float*)d_in[12];

    float* ws  = (float*)d_ws;
    float* g   = ws;            // 64
    float* eus = ws + 64;       // 256 (eu * softmax scale)
    float* ev  = ws + 320;      // 256
    float* po  = ws + 576;      // 2048
    float* pg  = ws + 2624;     // 2048
    float* out = (float*)d_out;

    k_obs_enc<<<2048, 256, 0, stream>>>(W1, obs, token_ids, emb_table, Wih, Whh,
                                        bih, bhh, f1W, g, eus, ev, po);
    k_gp<<<2048, 256, 0, stream>>>(W1, g, eus, ev, pg);
    k_finish<<<1, 512, 0, stream>>>(po, pg, b1, W2, b2, out);
}

// Round 4
// 71.865 us; speedup vs baseline: 1.4502x; 1.4502x over previous
//
#include <hip/hip_runtime.h>
#include <math.h>

#define H    64
#define N    256
#define D    128
#define L    16
#define SEG    448                 // cols per i-segment: 128 obs | 64 g | 256 p
#define SEG4   112                 // float4 per segment
#define F3IN (N * SEG)             // 114688
#define CHUNK_SEGS 64              // segments per block
#define CHUNK4 (CHUNK_SEGS * SEG4) // 7168 float4 per block

typedef float v4f __attribute__((ext_vector_type(4)));

__device__ __forceinline__ float sigmoidf_(float x) {
    return 1.0f / (1.0f + expf(-x));
}
__device__ __forceinline__ float dot4(float4 a, float4 b) {
    return a.x * b.x + a.y * b.y + a.z * b.z + a.w * b.w;
}

// ---------------------------------------------------------------------------
// Kernel 1: embedding gather + GRU (L=16) + f1W transform + factorized flat
// softmax. One block, 256 threads. Z_ij = u_i + v_j + const; const cancels.
// Outputs: g[64], eus[256] (= eu * 1/(Su*Sv)), ev[256].
// ---------------------------------------------------------------------------
__global__ __launch_bounds__(256) void k_enc(
    const int* __restrict__ token_ids, const float* __restrict__ emb_table,
    const float* __restrict__ Wih, const float* __restrict__ Whh,
    const float* __restrict__ bih, const float* __restrict__ bhh,
    const float* __restrict__ f1W, const float* __restrict__ obs,
    float* __restrict__ g_out, float* __restrict__ eus_out,
    float* __restrict__ ev_out)
{
    __shared__ float emb[L][H];
    __shared__ float h[H];
    __shared__ float hnew[H];
    __shared__ float gi_s[3 * H];
    __shared__ float gh_s[3 * H];
    __shared__ float wa_s[D];
    __shared__ float wb_s[D];
    __shared__ float red[256];

    const int k = threadIdx.x;

    for (int idx = k; idx < L * H; idx += 256) {
        int t = idx >> 6, d = idx & 63;
        emb[t][d] = emb_table[token_ids[t] * H + d];
    }
    if (k < H) h[k] = 0.0f;

    // threads 0..191: register-cache gate rows of Wih/Whh
    float4 wih4[16], whh4[16];
    float bi = 0.0f, bh = 0.0f;
    if (k < 3 * H) {
        const float4* wi = (const float4*)(Wih + k * H);
        const float4* wh = (const float4*)(Whh + k * H);
#pragma unroll
        for (int c = 0; c < 16; ++c) { wih4[c] = wi[c]; whh4[c] = wh[c]; }
        bi = bih[k]; bh = bhh[k];
    }
    __syncthreads();

    for (int t = 0; t < L; ++t) {
        if (k < 3 * H) {
            const float4* et = (const float4*)emb[t];
            const float4* hv = (const float4*)h;
            float gi = bi, gh = bh;
#pragma unroll
            for (int c = 0; c < 16; ++c) {
                gi += dot4(wih4[c], et[c]);
                gh += dot4(whh4[c], hv[c]);
            }
            gi_s[k] = gi;
            gh_s[k] = gh;
        }
        __syncthreads();
        if (k < H) {
            float r = sigmoidf_(gi_s[k] + gh_s[k]);
            float z = sigmoidf_(gi_s[H + k] + gh_s[H + k]);
            float n = tanhf(gi_s[2 * H + k] + r * gh_s[2 * H + k]);
            hnew[k] = (1.0f - z) * n + z * h[k];
        }
        __syncthreads();
        if (k < H) h[k] = hnew[k];
        __syncthreads();
    }

    // wa = f1W[:, :128]^T h ; wb = f1W[:, 128:]^T h  (coalesced over k)
    {
        float s = 0.0f;
#pragma unroll 8
        for (int kk = 0; kk < H; ++kk) s += f1W[kk * (2 * D) + k] * h[kk];
        if (k < D) wa_s[k] = s;
        else       wb_s[k - D] = s;
        if (k < H) g_out[k] = h[k];
    }
    __syncthreads();

    // u_i = obs_i . wa ; v_i = obs_i . wb  (thread = row i)
    const float4* rowp = (const float4*)(obs + k * D);
    const float4* wav = (const float4*)wa_s;
    const float4* wbv = (const float4*)wb_s;
    float u = 0.0f, v = 0.0f;
#pragma unroll
    for (int c = 0; c < D / 4; ++c) {
        float4 o = rowp[c];
        u += dot4(o, wav[c]);
        v += dot4(o, wbv[c]);
    }

    red[k] = u; __syncthreads();
    for (int s = 128; s > 0; s >>= 1) { if (k < s) red[k] = fmaxf(red[k], red[k + s]); __syncthreads(); }
    const float mu = red[0]; __syncthreads();
    const float eui = expf(u - mu);
    red[k] = eui; __syncthreads();
    for (int s = 128; s > 0; s >>= 1) { if (k < s) red[k] += red[k + s]; __syncthreads(); }
    const float Su = red[0]; __syncthreads();

    red[k] = v; __syncthreads();
    for (int s = 128; s > 0; s >>= 1) { if (k < s) red[k] = fmaxf(red[k], red[k + s]); __syncthreads(); }
    const float mv = red[0]; __syncthreads();
    const float evi = expf(v - mv);
    red[k] = evi; __syncthreads();
    for (int s = 128; s > 0; s >>= 1) { if (k < s) red[k] += red[k + s]; __syncthreads(); }
    const float Sv = red[0];

    eus_out[k] = eui * (1.0f / (Su * Sv));   // softmax scale folded into eu
    ev_out[k]  = evi;
}

// ---------------------------------------------------------------------------
// Kernel 2: fused matvec over W1 with VIRTUAL x. W1 is streamed in one fully
// contiguous pass (224 MiB); each float4 is contracted against obs (L2) /
// g (LDS) / eu_i*ev (LDS) per its column zone. 2048 blocks = 512 rows x 4.
// ---------------------------------------------------------------------------
__global__ __launch_bounds__(256, 4) void k_mv(
    const float* __restrict__ W1, const float* __restrict__ obs,
    const float* __restrict__ g, const float* __restrict__ eus,
    const float* __restrict__ ev, float* __restrict__ partial)
{
    __shared__ float g_s[64];
    __shared__ float ev_s[256];
    __shared__ float eu_s[64];
    __shared__ float red[256];

    const int t = threadIdx.x;
    const int row = blockIdx.x >> 2, q = blockIdx.x & 3;

    if (t < 64) { g_s[t] = g[t]; eu_s[t] = eus[q * 64 + t]; }
    ev_s[t] = ev[t];
    __syncthreads();

    const v4f* wb = (const v4f*)W1 + (size_t)row * (F3IN / 4) + (size_t)q * CHUNK4;
    const float4* obs4 = (const float4*)obs + q * CHUNK_SEGS * (D / 4);

    float a0 = 0.0f, a1 = 0.0f, a2 = 0.0f, a3 = 0.0f;
#pragma unroll 7
    for (int k = 0; k < 28; ++k) {
        const int idx = t + k * 256;          // < 7168
        const int seg = idx / SEG4;
        const int c4  = idx - seg * SEG4;
        v4f w = __builtin_nontemporal_load(wb + idx);
        float4 o;
        if (c4 < 32) {
            o = obs4[seg * 32 + c4];
        } else if (c4 < 48) {
            o = ((const float4*)g_s)[c4 - 32];
        } else {
            float4 e = ((const float4*)ev_s)[c4 - 48];
            float m = eu_s[seg];
            o = make_float4(e.x * m, e.y * m, e.z * m, e.w * m);
        }
        float d = w[0] * o.x + w[1] * o.y + w[2] * o.z + w[3] * o.w;
        switch (k & 3) {
            case 0: a0 += d; break;
            case 1: a1 += d; break;
            case 2: a2 += d; break;
            default: a3 += d; break;
        }
    }
    float sum = (a0 + a1) + (a2 + a3);

    red[t] = sum; __syncthreads();
    for (int s = 128; s > 0; s >>= 1) {
        if (t < s) red[t] += red[t + s];
        __syncthreads();
    }
    if (t == 0) partial[blockIdx.x] = red[0];
}

// ---------------------------------------------------------------------------
// Kernel 3: h1 = relu(sum of 4 partials + b1); out = W2 @ h1 + b2. One block.
// ---------------------------------------------------------------------------
__global__ __launch_bounds__(512) void k_finish(
    const float* __restrict__ partial, const float* __restrict__ b1,
    const float* __restrict__ W2, const float* __restrict__ b2,
    float* __restrict__ out)
{
    __shared__ float h1s[512];
    const int r = threadIdx.x;
    {
        float4 p = ((const float4*)partial)[r];
        h1s[r] = fmaxf(p.x + p.y + p.z + p.w + b1[r], 0.0f);
    }
    __syncthreads();

    const int wave = r >> 6, lane = r & 63;
    for (int row = wave; row < 40; row += 8) {
        float s = 0.0f;
#pragma unroll
        for (int c = 0; c < 8; ++c)
            s += W2[row * 512 + lane + c * 64] * h1s[lane + c * 64];
#pragma unroll
        for (int off = 32; off > 0; off >>= 1) s += __shfl_down(s, off, 64);
        if (lane == 0) out[row] = s + b2[row];
    }
}

// ---------------------------------------------------------------------------
extern "C" void kernel_launch(void* const* d_in, const int* in_sizes, int n_in,
                              void* d_out, int out_size, void* d_ws, size_t ws_size,
                              hipStream_t stream)
{
    const float* obs       = (const float*)d_in[0];
    const int*   token_ids = (const int*)  d_in[1];
    const float* emb_table = (const float*)d_in[2];
    const float* Wih       = (const float*)d_in[3];
    const float* Whh       = (const float*)d_in[4];
    const float* bih       = (const float*)d_in[5];
    const float* bhh       = (const float*)d_in[6];
    const float* f1W       = (const float*)d_in[7];
    // d_in[8] = f1_b : cancels in the flat softmax (Z_ij = u_i + v_j + const)
    const float* W1        = (const float*)d_in[9];
    const float* b1        = (const float*)d_in[10];
    const float* W2        = (const float*)d_in[11];
    const float* b2        = (const float*)d_in[12];

    float* ws   = (float*)d_ws;
    float* g    = ws;          // 64
    float* eus  = ws + 64;     // 256
    float* ev   = ws + 320;    // 256
    float* part = ws + 576;    // 2048
    float* out  = (float*)d_out;

    k_enc<<<1, 256, 0, stream>>>(token_ids, emb_table, Wih, Whh, bih, bhh,
                                 f1W, obs, g, eus, ev);
    k_mv<<<2048, 256, 0, stream>>>(W1, obs, g, eus, ev, part);
    k_finish<<<1, 512, 0, stream>>>(part, b1, W2, b2, out);
}